// Round 7
// baseline (81.339 us; speedup 1.0000x reference)
//
#include <hip/hip_runtime.h>
#include <math.h>

#define HID 2880
#define NE  128
#define BK  32              // k per chunk
#define TOKB 64
#define NCHG 45             // chunks per ks-half (2 x 45 = 90)
#define PSTR 129

typedef _Float16 half4v __attribute__((ext_vector_type(4)));
typedef _Float16 half8v __attribute__((ext_vector_type(8)));
typedef float    f32x4v __attribute__((ext_vector_type(4)));

// ---------------- prep: split W fp32 -> f16 hi/lo, [chunk 90][e 128][k 32] ------
__global__ __launch_bounds__(256)
void prep_w(const float* __restrict__ W, _Float16* __restrict__ whi,
            _Float16* __restrict__ wlo)
{
    const int e = blockIdx.x;
    for (int j = 0; j < 12; ++j) {
        const int k = j * 256 + threadIdx.x;
        if (k >= HID) break;
        const float v = W[(size_t)e * HID + k];
        const _Float16 h = (_Float16)v;
        const _Float16 l = (_Float16)(v - (float)h);
        const size_t idx = (size_t)(k >> 5) * 4096 + e * 32 + (k & 31);
        whi[idx] = h;
        wlo[idx] = l;
    }
}

// asm-forced 16B global load: regs cannot be collapsed/sunk; order = issue order.
#define GLOAD(dst, ptr) \
    asm volatile("global_load_dwordx4 %0, %1, off" : "=v"(dst) : "v"(ptr))
#define GLOAD_O1024(dst, ptr) \
    asm volatile("global_load_dwordx4 %0, %1, off offset:1024" : "=v"(dst) : "v"(ptr))

// ---------------- fused: 16-wave 2-way k-split, 3-chunk epochs, 3 W reg-sets ------
// R6 synthesis: barrier-count regression line (R0 16bar=65.3, R3 11bar=66.8,
// R6-cells 60bar=74.0) shows schedule variants only move the ~0.15us/barrier
// term; the ~65us base is invariant at 12 waves (3/SIMD) with all pipes <30%.
// Single-variable test: 4 waves/SIMD, structure held. 1024 thr = 16 waves =
// ks(2) x th(2) x wq(4): k-halves (45 chunks), token-halves (32), experts x32.
// Same 6-slot swizzled ring per ks, 3 W sets, R4 FIFO-clean ledger: W(b+1),
// W(b+2) at epoch top BEFORE A; S0 refilled right after its MFMAs; A last
// (newest). Waits: c0 none, c1 VMC(11) (retires S1 only), c2 VMC(7) (S2 only),
// epoch end VMC(0)+CONVA+one lgkm barrier. acc[2][2] keeps regs <=128 (hard
// requirement for a 1024-thread block). Deterministic 2-way k-combine.
__global__ __launch_bounds__(1024, 4)
void fused_router(const float* __restrict__ A, const _Float16* __restrict__ whi,
                  const _Float16* __restrict__ wlo, const float* __restrict__ bias,
                  float* __restrict__ scores, float* __restrict__ idxOut,
                  float* __restrict__ counts)
{
    // ring: [ks 2][slot 6][h 2][64 tok][32 k f16] = 2*6*8192 = 98304 B
    __shared__ __align__(16) char smem[98304];
    __shared__ float sval[TOKB][4];
    __shared__ int   sidx[TOKB][4];
    __shared__ int   hist[NE];

#define SWZ(tok) ((((tok) >> 1) & 3) << 4)

    const int tid  = threadIdx.x;
    const int lane = tid & 63;
    const int wv   = __builtin_amdgcn_readfirstlane(tid >> 6);   // 0..15
    const int ks   = wv >> 3;        // k-half 0..1
    const int sub  = wv & 7;
    const int wq   = sub & 3;        // expert group 0..3
    const int th   = sub >> 2;       // token half 0..1
    const int lg   = lane >> 4;      // k-quarter 0..3
    const int lr   = lane & 15;
    const int tokBase = blockIdx.x * TOKB;
    const int hbeg = ks * NCHG;      // first global chunk of this k-half

    // W per-lane fragment base (m=0): e = wq*32 + lr, k-off lg*8.
    // m=1 adds 16 experts * 32 halves = 1024 B -> offset:1024 immediate.
    const _Float16* wHp0 = whi + (size_t)((wq * 32 + lr) * 32 + lg * 8);
    const _Float16* wLp0 = wlo + (size_t)((wq * 32 + lr) * 32 + lg * 8);

    // A producer: ks-half's 512 threads stage 64 tok x 32 k per chunk;
    // thread -> (tok, 4-float k-part): 1 dwordx4 per chunk.
    const int gid  = tid & 511;
    const int ptok = gid >> 3;
    const int part = gid & 7;
    const float* aSrc = A + (size_t)(tokBase + ptok) * HID + ks * 1440 + part * 4;
    const int aWr = ptok * 64 + ((part * 8) ^ SWZ(ptok));   // swizzled byte off

    // A consumer byte offsets: token th*32 + n*16 + lr, k-quarter lg (same swz)
    int aRd[2];
#pragma unroll
    for (int n = 0; n < 2; ++n) {
        const int tok = th * 32 + n * 16 + lr;
        aRd[n] = tok * 64 + ((lg * 16) ^ SWZ(tok));
    }

    // W set: [m*2 + hl] -> 4 half8v = 16 VGPR forced
#define WISSUE(SET, ch) do {                                                   \
    const _Float16* hp_ = wHp0 + (size_t)(ch) * 4096;                          \
    const _Float16* lp_ = wLp0 + (size_t)(ch) * 4096;                          \
    GLOAD(SET[0], hp_);                                                        \
    GLOAD(SET[1], lp_);                                                        \
    GLOAD_O1024(SET[2], hp_);                                                  \
    GLOAD_O1024(SET[3], lp_);                                                  \
} while (0)

    // convert one chunk's A regs (1 float4) -> hi/lo half4, write ring slot
#define CONVA1(AX, SLOT) do {                                                  \
    const _Float16 h0=(_Float16)AX.x, h1=(_Float16)AX.y,                       \
                   h2=(_Float16)AX.z, h3=(_Float16)AX.w;                       \
    const half4v hh = {h0,h1,h2,h3};                                           \
    const half4v ll = {(_Float16)(AX.x-(float)h0),(_Float16)(AX.y-(float)h1),  \
                       (_Float16)(AX.z-(float)h2),(_Float16)(AX.w-(float)h3)}; \
    char* wb_ = smem + ks * 49152 + (SLOT) * 8192 + aWr;                       \
    *reinterpret_cast<half4v*>(wb_)        = hh;                               \
    *reinterpret_cast<half4v*>(wb_ + 4096) = ll;                               \
} while (0)

    // consume one chunk from ring slot with W register set (12 MFMA)
#define CCHUNK(SLOT, SET) do {                                                 \
    const char* b0_ = smem + ks * 49152 + (SLOT) * 8192;                       \
    _Pragma("unroll")                                                          \
    for (int n = 0; n < 2; ++n) {                                              \
        const half8v ah = *reinterpret_cast<const half8v*>(b0_ + aRd[n]);      \
        const half8v al = *reinterpret_cast<const half8v*>(b0_ + 4096 + aRd[n]);\
        _Pragma("unroll")                                                      \
        for (int m = 0; m < 2; ++m) {                                          \
            acc[m][n] = __builtin_amdgcn_mfma_f32_16x16x32_f16(                \
                SET[m * 2 + 0], ah, acc[m][n], 0, 0, 0);                       \
            acc[m][n] = __builtin_amdgcn_mfma_f32_16x16x32_f16(                \
                SET[m * 2 + 1], ah, acc[m][n], 0, 0, 0);                       \
            acc[m][n] = __builtin_amdgcn_mfma_f32_16x16x32_f16(                \
                SET[m * 2 + 0], al, acc[m][n], 0, 0, 0);                       \
        }                                                                      \
    }                                                                          \
} while (0)

#define VMC(n) do {                                                            \
    asm volatile("s_waitcnt vmcnt(" #n ")" ::: "memory");                      \
    __builtin_amdgcn_sched_barrier(0);                                         \
} while (0)

#define SB0   __builtin_amdgcn_sched_barrier(0)
#define LGKM0 do { asm volatile("s_waitcnt lgkmcnt(0)" ::: "memory"); SB0; } while (0)
#define BAR   do { SB0; __builtin_amdgcn_s_barrier(); SB0; } while (0)

    f32x4v acc[2][2];
#pragma unroll
    for (int m = 0; m < 2; ++m)
#pragma unroll
        for (int n = 0; n < 2; ++n) acc[m][n] = (f32x4v)0.f;

    half8v wS0[4], wS1[4], wS2[4];
    float4 aR0, aR1, aR2;

    // stage A-group (3 chunks at group-local chunk B_), 1 dwordx4 each
#define ASTAGE(B_) do {                                                        \
    const float* p_ = aSrc + (size_t)(B_) * BK;                                \
    GLOAD(aR0, p_);                                                            \
    GLOAD(aR1, p_ + BK);                                                       \
    GLOAD(aR2, p_ + 2 * BK);                                                   \
} while (0)

    // EPOCH(E, CS, PS, STAGE, LAST): consume chunks 3E..3E+2 (slots CS..CS+2)
    // with sets S0/S1/S2. S1,S2 issue at top BEFORE A; S0(b+3) refilled after
    // c0's MFMAs; A last (newest in FIFO).
    // Ledger (steady): top +S1(4)+S2(4)+A(3)=11; after S0 refill 15;
    // VMC(11) retires S1; VMC(7) retires S2 (A3+S0r4 left); VMC(0) end.
#define EPOCH(E, CS, PS, STAGE, LAST) do {                                     \
    const int b_ = 3 * (E);                                                    \
    WISSUE(wS1, hbeg + b_ + 1);                                                \
    WISSUE(wS2, hbeg + b_ + 2);                                                \
    if (STAGE) ASTAGE(b_ + 3);                                                 \
    SB0;                                                                       \
    CCHUNK((CS) + 0, wS0);                                                     \
    SB0;                                                                       \
    if (!(LAST)) { WISSUE(wS0, hbeg + b_ + 3); }                               \
    SB0;                                                                       \
    if (LAST) VMC(4); else VMC(11);                                            \
    CCHUNK((CS) + 1, wS1);                                                     \
    SB0;                                                                       \
    if (LAST) VMC(0); else VMC(7);                                             \
    CCHUNK((CS) + 2, wS2);                                                     \
    if (STAGE) {                                                               \
        VMC(0);                                                                \
        CONVA1(aR0, (PS) + 0);                                                 \
        CONVA1(aR1, (PS) + 1);                                                 \
        CONVA1(aR2, (PS) + 2);                                                 \
        LGKM0;                                                                 \
        BAR;                                                                   \
    }                                                                          \
} while (0)

    // prologue: A(0..2) + W(0)->wS0; drain; CONVA slots 0..2; publish.
    ASTAGE(0);
    WISSUE(wS0, hbeg + 0);
    VMC(0);
    CONVA1(aR0, 0);
    CONVA1(aR1, 1);
    CONVA1(aR2, 2);
    LGKM0;
    BAR;

    // epochs 0..13 (paired even/odd, staging), 14 (even, final)
#pragma unroll 1
    for (int e = 0; e < 14; e += 2) {
        EPOCH(e,     0, 3, 1, 0);
        EPOCH(e + 1, 3, 0, 1, 0);
    }
    EPOCH(14, 0, 3, 0, 1);

    __syncthreads();   // all ring reads done before epilogue overlay

    // ---------------- epilogue: deterministic 2-way reduction ----------------
    float* P1   = (float*)(smem);            // 64*129*4 = 33024 B (overlay)
    float* cval = (float*)(smem + 33024);    // 64*33*4 = 8448 B
    int*   cidx = (int*)(smem + 41472);      // 8448 B

    if (tid < NE) hist[tid] = 0;

    // ks=1 partials -> LDS
    if (ks == 1) {
#pragma unroll
        for (int m = 0; m < 2; ++m)
#pragma unroll
            for (int n = 0; n < 2; ++n)
#pragma unroll
                for (int r = 0; r < 4; ++r) {
                    const int e = wq * 32 + m * 16 + lg * 4 + r;
                    const int t = th * 32 + n * 16 + lr;
                    P1[t * PSTR + e] = acc[m][n][r];
                }
    }
    __syncthreads();

    // ks=0 combines in fixed order -> logits in P1
    if (ks == 0) {
#pragma unroll
        for (int m = 0; m < 2; ++m)
#pragma unroll
            for (int n = 0; n < 2; ++n)
#pragma unroll
                for (int r = 0; r < 4; ++r) {
                    const int e = wq * 32 + m * 16 + lg * 4 + r;
                    const int t = th * 32 + n * 16 + lr;
                    const int off = t * PSTR + e;
                    P1[off] = (acc[m][n][r] + P1[off]) + bias[e];
                }
    }
    __syncthreads();

    // top-4 candidates: 64 tok x 8 groups of 16 experts (threads 0..511)
    if (tid < 512) {
        const int t = tid & 63, g = tid >> 6;
        float v0 = -1e30f, v1 = -1e30f, v2 = -1e30f, v3 = -1e30f;
        int   i0 = 0, i1 = 0, i2 = 0, i3 = 0;
        const int e0 = g * 16;
#pragma unroll 4
        for (int i = 0; i < 16; ++i) {
            const int e = e0 + i;
            const float v = P1[t * PSTR + e];
            if (v > v3) {
                if (v > v2) {
                    v3 = v2; i3 = i2;
                    if (v > v1) {
                        v2 = v1; i2 = i1;
                        if (v > v0) { v1 = v0; i1 = i0; v0 = v; i0 = e; }
                        else        { v1 = v;  i1 = e; }
                    } else { v2 = v; i2 = e; }
                } else { v3 = v; i3 = e; }
            }
        }
        cval[t * 33 + g * 4 + 0] = v0; cidx[t * 33 + g * 4 + 0] = i0;
        cval[t * 33 + g * 4 + 1] = v1; cidx[t * 33 + g * 4 + 1] = i1;
        cval[t * 33 + g * 4 + 2] = v2; cidx[t * 33 + g * 4 + 2] = i2;
        cval[t * 33 + g * 4 + 3] = v3; cidx[t * 33 + g * 4 + 3] = i3;
    }
    __syncthreads();

    if (tid < TOKB) {
        const int t = tid;
        float m0 = -1e30f, m1 = -1e30f, m2 = -1e30f, m3 = -1e30f;
        int   j0 = 0, j1 = 0, j2 = 0, j3 = 0;
#pragma unroll
        for (int q = 0; q < 32; ++q) {   // group-major, ascending e within group
            const float v = cval[t * 33 + q];
            const int   e = cidx[t * 33 + q];
            if (v > m3) {
                if (v > m2) {
                    m3 = m2; j3 = j2;
                    if (v > m1) {
                        m2 = m1; j2 = j1;
                        if (v > m0) { m1 = m0; j1 = j0; m0 = v; j0 = e; }
                        else        { m1 = v;  j1 = e; }
                    } else { m2 = v; j2 = e; }
                } else { m3 = v; j3 = e; }
            }
        }
        const float x1 = expf(m1 - m0), x2 = expf(m2 - m0), x3 = expf(m3 - m0);
        const float inv = 1.f / (1.f + x1 + x2 + x3);
        sval[t][0] = inv;      sidx[t][0] = j0;
        sval[t][1] = x1 * inv; sidx[t][1] = j1;
        sval[t][2] = x2 * inv; sidx[t][2] = j2;
        sval[t][3] = x3 * inv; sidx[t][3] = j3;
        atomicAdd(&hist[j0], 1); atomicAdd(&hist[j1], 1);
        atomicAdd(&hist[j2], 1); atomicAdd(&hist[j3], 1);
    }
    __syncthreads();

    // dense score scatter: 64 tok x 128 exp = 8192 floats, coalesced (8 iters)
    const size_t sBase = (size_t)blockIdx.x * TOKB * NE;
#pragma unroll 4
    for (int it = 0; it < 8; ++it) {
        const int flat = it * 1024 + tid;
        const int t = flat >> 7, e = flat & 127;
        float val = 0.f;
        val = (e == sidx[t][0]) ? sval[t][0] : val;
        val = (e == sidx[t][1]) ? sval[t][1] : val;
        val = (e == sidx[t][2]) ? sval[t][2] : val;
        val = (e == sidx[t][3]) ? sval[t][3] : val;
        scores[sBase + flat] = val;
    }
    // indices as float32: 256 per block
    if (tid < TOKB * 4)
        idxOut[(size_t)blockIdx.x * TOKB * 4 + tid] =
            (float)sidx[tid >> 2][tid & 3];
    if (tid < NE) {
        const int c = hist[tid];
        if (c) atomicAdd(&counts[tid], (float)c);
    }
#undef SWZ
#undef WISSUE
#undef CONVA1
#undef CCHUNK
#undef VMC
#undef SB0
#undef LGKM0
#undef BAR
#undef ASTAGE
#undef EPOCH
}

extern "C" void kernel_launch(void* const* d_in, const int* in_sizes, int n_in,
                              void* d_out, int out_size, void* d_ws, size_t ws_size,
                              hipStream_t stream) {
    const float* A = (const float*)d_in[0];   // hidden_states [T, 2880]
    const float* W = (const float*)d_in[1];   // weight [128, 2880]
    const float* B = (const float*)d_in[2];   // bias [128]
    const int T = in_sizes[0] / HID;          // 16384

    float* out = (float*)d_out;
    float* scores = out;                          // [T,128]
    float* idxOut = out + (size_t)T * NE;         // [T,4] as float
    float* counts = idxOut + (size_t)T * 4;       // [128] as float

    _Float16* whi = (_Float16*)d_ws;              // [90][128][32] halves
    _Float16* wlo = whi + (size_t)NE * HID;

    hipMemsetAsync(counts, 0, NE * sizeof(float), stream);

    hipLaunchKernelGGL(prep_w, dim3(NE), dim3(256), 0, stream, W, whi, wlo);
    hipLaunchKernelGGL(fused_router, dim3(T / TOKB), dim3(1024), 0, stream,
                       A, whi, wlo, B, scores, idxOut, counts);
}

// Round 8
// 74.552 us; speedup vs baseline: 1.0910x; 1.0910x over previous
//
#include <hip/hip_runtime.h>
#include <math.h>

#define HID 2880
#define NE  128
#define BK  64              // k per chunk (2 x 32)
#define TOKB 64
#define HN  15              // chunks per k-third
#define PSTR 129

typedef _Float16 half4v __attribute__((ext_vector_type(4)));
typedef _Float16 half8v __attribute__((ext_vector_type(8)));
typedef float    f32x4v __attribute__((ext_vector_type(4)));

// ---------------- prep: split W fp32 -> f16 hi/lo, [kt 45][sub 2][e 128][k 32] ------
__global__ __launch_bounds__(256)
void prep_w(const float* __restrict__ W, _Float16* __restrict__ whi,
            _Float16* __restrict__ wlo)
{
    const int e = blockIdx.x;
    for (int j = 0; j < 12; ++j) {
        const int k = j * 256 + threadIdx.x;
        if (k >= HID) break;
        const float v = W[(size_t)e * HID + k];
        const _Float16 h = (_Float16)v;
        const _Float16 l = (_Float16)(v - (float)h);
        const size_t idx = (size_t)(k >> 6) * 8192 + ((k >> 5) & 1) * 4096
                         + e * 32 + (k & 31);
        whi[idx] = h;
        wlo[idx] = l;
    }
}

// asm-forced 16B global load: regs cannot be collapsed/sunk; order = issue order.
#define GLOAD(dst, ptr) \
    asm volatile("global_load_dwordx4 %0, %1, off" : "=v"(dst) : "v"(ptr))

// ---------------- main: one block = one (64-token, k-third) pipeline --------------
// R7 synthesis: more waves per barrier domain = worse (R2 24w=82, R7 16w=81,
// R0 12w=65); all-coupled schedules pin at 65+. Never isolated: the 3 k-groups
// share one barrier domain. Here each k-third is its OWN 256-thr block (4-wave
// barrier domain), grid 768 = 256 tok-tiles x 3 ks, 3 blocks/CU — same 12
// waves/CU as R0 but three independently-slipping pipelines per CU. Per-block
// structure = R0's proven per-ks-group loop verbatim (BK=64, 15 steps, two-set
// W alternation, vmcnt(12)/(8), swizzled staging). Partials to global; tiny
// reduce kernel combines in R0's exact float order.
__global__ __launch_bounds__(256, 3)
void fused_router(const float* __restrict__ A, const _Float16* __restrict__ whi,
                  const _Float16* __restrict__ wlo, float* __restrict__ p0,
                  float* __restrict__ p1, float* __restrict__ p2)
{
    // staging: [buf2][h2][sub2][64 tok][32 k] halves = 32 KB
    __shared__ __align__(16) char smem[32768];

#define SA(buf, h, sub) (smem + ((((buf) * 2 + (h)) * 2 + (sub)) * 4096))
#define SWZ(tok) ((((tok) >> 1) & 3) << 4)

    const int tid  = threadIdx.x;
    const int lane = tid & 63;
    const int wq   = __builtin_amdgcn_readfirstlane(tid >> 6);   // expert group
    const int bid  = blockIdx.x;
    const int ks   = bid % 3;                   // k-third
    const int tb   = bid / 3;                   // token tile
    const int lg   = lane >> 4;
    const int lr   = lane & 15;
    const int tokBase = tb * TOKB;
    const int hbeg = ks * HN;

    // W per-lane fragment bases (halves): e = wq*32 + m*16 + lr, k-off lg*8
    const _Float16* wHp[2];
    const _Float16* wLp[2];
#pragma unroll
    for (int m = 0; m < 2; ++m) {
        const size_t b = (size_t)((wq * 32 + m * 16 + lr) * 32 + lg * 8);
        wHp[m] = whi + b;
        wLp[m] = wlo + b;
    }

    // A producers: 256 threads stage 64 tok x 16 f4-slots; 4/thread
    const float* aSrcP[4];
    int aSub[4], aWr[4];
#pragma unroll
    for (int p = 0; p < 4; ++p) {
        const int f = p * 256 + tid;
        const int tok = f >> 4, sl = f & 15;
        aSub[p] = sl >> 3;
        const int q = sl & 7;
        aSrcP[p] = A + (size_t)(tokBase + tok) * HID + ks * 960 + aSub[p] * 32 + q * 4;
        aWr[p] = tok * 64 + ((q * 8) ^ SWZ(tok));
    }

    // A consumer byte offsets: token n*16+lr, k-quarter lg (same swizzle)
    int aRd[4];
#pragma unroll
    for (int n = 0; n < 4; ++n) {
        const int tok = n * 16 + lr;
        aRd[n] = tok * 64 + ((lg * 16) ^ SWZ(tok));
    }

    float4 aA, aB, aC, aD;
#define AISSUE(c) do {                                                         \
    GLOAD(aA, aSrcP[0] + (size_t)(c) * BK);                                    \
    GLOAD(aB, aSrcP[1] + (size_t)(c) * BK);                                    \
    GLOAD(aC, aSrcP[2] + (size_t)(c) * BK);                                    \
    GLOAD(aD, aSrcP[3] + (size_t)(c) * BK);                                    \
} while (0)

    // W set: [m*4 + s*2 + hl] -> 8 half8v = 32 VGPR forced
#define WISSUE(SET, c) do {                                                    \
    _Pragma("unroll")                                                          \
    for (int m = 0; m < 2; ++m)                                                \
        _Pragma("unroll")                                                      \
        for (int s = 0; s < 2; ++s) {                                          \
            const size_t o = (size_t)(c) * 8192 + s * 4096;                    \
            GLOAD(SET[m * 4 + s * 2 + 0], wHp[m] + o);                         \
            GLOAD(SET[m * 4 + s * 2 + 1], wLp[m] + o);                         \
        }                                                                      \
} while (0)

    auto CONVA = [&](int buf) {
#pragma unroll
        for (int p = 0; p < 4; ++p) {
            const float4 v = (p == 0) ? aA : (p == 1) ? aB : (p == 2) ? aC : aD;
            const _Float16 h0 = (_Float16)v.x, h1 = (_Float16)v.y,
                           h2 = (_Float16)v.z, h3 = (_Float16)v.w;
            const half4v hh = {h0, h1, h2, h3};
            const half4v ll = {(_Float16)(v.x - (float)h0),
                               (_Float16)(v.y - (float)h1),
                               (_Float16)(v.z - (float)h2),
                               (_Float16)(v.w - (float)h3)};
            *reinterpret_cast<half4v*>(SA(buf, 0, aSub[p]) + aWr[p]) = hh;
            *reinterpret_cast<half4v*>(SA(buf, 1, aSub[p]) + aWr[p]) = ll;
        }
    };

    f32x4v acc[2][4];
#pragma unroll
    for (int m = 0; m < 2; ++m)
#pragma unroll
        for (int n = 0; n < 4; ++n) acc[m][n] = (f32x4v)0.f;

    half8v wA[8], wB[8];

#define STEP(i, SU, SF) do {                                                   \
    if ((i) + 1 < HN) { AISSUE((i) + 1); WISSUE(SF, hbeg + (i) + 1); }         \
    __builtin_amdgcn_sched_barrier(0);                                         \
    if ((i) + 1 < HN) asm volatile("s_waitcnt vmcnt(12)" ::: "memory");        \
    else              asm volatile("s_waitcnt vmcnt(0)" ::: "memory");         \
    __builtin_amdgcn_sched_barrier(0);                                         \
    const int buf_ = (i) & 1;                                                  \
    _Pragma("unroll")                                                          \
    for (int s = 0; s < 2; ++s)                                                \
        _Pragma("unroll")                                                      \
        for (int n = 0; n < 4; ++n) {                                          \
            const half8v ah = *reinterpret_cast<const half8v*>(                \
                SA(buf_, 0, s) + aRd[n]);                                      \
            const half8v al = *reinterpret_cast<const half8v*>(                \
                SA(buf_, 1, s) + aRd[n]);                                      \
            _Pragma("unroll")                                                  \
            for (int m = 0; m < 2; ++m) {                                      \
                acc[m][n] = __builtin_amdgcn_mfma_f32_16x16x32_f16(            \
                    SU[m * 4 + s * 2 + 0], ah, acc[m][n], 0, 0, 0);            \
                acc[m][n] = __builtin_amdgcn_mfma_f32_16x16x32_f16(            \
                    SU[m * 4 + s * 2 + 1], ah, acc[m][n], 0, 0, 0);            \
                acc[m][n] = __builtin_amdgcn_mfma_f32_16x16x32_f16(            \
                    SU[m * 4 + s * 2 + 0], al, acc[m][n], 0, 0, 0);            \
            }                                                                  \
        }                                                                      \
    if ((i) + 1 < HN) {                                                        \
        asm volatile("s_waitcnt vmcnt(8)" ::: "memory");                       \
        __builtin_amdgcn_sched_barrier(0);                                     \
        CONVA(((i) + 1) & 1);                                                  \
    }                                                                          \
    asm volatile("s_waitcnt lgkmcnt(0)" ::: "memory");                         \
    __builtin_amdgcn_sched_barrier(0);                                         \
    __builtin_amdgcn_s_barrier();                                              \
    __builtin_amdgcn_sched_barrier(0);                                         \
} while (0)

    // prologue: A(0)[4] + W(hbeg)->wA[8]; vmcnt(8) retires A; publish buf0
    AISSUE(0);
    WISSUE(wA, hbeg);
    asm volatile("s_waitcnt vmcnt(8)" ::: "memory");
    __builtin_amdgcn_sched_barrier(0);
    CONVA(0);
    asm volatile("s_waitcnt lgkmcnt(0)" ::: "memory");
    __builtin_amdgcn_sched_barrier(0);
    __builtin_amdgcn_s_barrier();
    __builtin_amdgcn_sched_barrier(0);

#pragma unroll 1
    for (int i = 0; i < HN - 1; i += 2) {
        STEP(i,     wA, wB);
        STEP(i + 1, wB, wA);
    }
    STEP(HN - 1, wA, wB);     // HN odd: last chunk uses set A, no issues

    // ---------------- epilogue: write 64x128 partial, coalesced f32x4 ---------
    float* P = (ks == 0) ? p0 : (ks == 1) ? p1 : p2;
#pragma unroll
    for (int m = 0; m < 2; ++m)
#pragma unroll
        for (int n = 0; n < 4; ++n) {
            const int e = wq * 32 + m * 16 + lg * 4;
            const int t = n * 16 + lr;
            *reinterpret_cast<f32x4v*>(
                &P[(size_t)(tokBase + t) * NE + e]) = acc[m][n];
        }
#undef SA
#undef SWZ
#undef AISSUE
#undef WISSUE
#undef STEP
}

// ---------------- reduce: combine partials (R0 float order), top-4, outputs -------
__global__ __launch_bounds__(512)
void reduce_router(float* __restrict__ scores, const float* __restrict__ p1,
                   const float* __restrict__ p2, const float* __restrict__ bias,
                   float* __restrict__ idxOut, float* __restrict__ counts)
{
    __shared__ float P[TOKB * PSTR];         // 33024 B
    __shared__ float cval[TOKB * 33];
    __shared__ int   cidx[TOKB * 33];
    __shared__ float sval[TOKB][4];
    __shared__ int   sidx[TOKB][4];
    __shared__ int   hist[NE];

    const int tid = threadIdx.x;
    const int tb  = blockIdx.x;
    const size_t base = (size_t)tb * TOKB * NE;

    if (tid < NE) hist[tid] = 0;

    // combine: identical float order to R0's ((p0 + p1) + p2) + bias
#pragma unroll
    for (int it = 0; it < 16; ++it) {
        const int flat = it * 512 + tid;
        const int t = flat >> 7, e = flat & 127;
        P[t * PSTR + e] = ((scores[base + flat] + p1[base + flat])
                           + p2[base + flat]) + bias[e];
    }
    __syncthreads();

    // top-4 candidates: 64 tok x 8 groups of 16 experts
    {
        const int t = tid & 63, g = tid >> 6;
        float v0 = -1e30f, v1 = -1e30f, v2 = -1e30f, v3 = -1e30f;
        int   i0 = 0, i1 = 0, i2 = 0, i3 = 0;
        const int e0 = g * 16;
#pragma unroll 4
        for (int i = 0; i < 16; ++i) {
            const int e = e0 + i;
            const float v = P[t * PSTR + e];
            if (v > v3) {
                if (v > v2) {
                    v3 = v2; i3 = i2;
                    if (v > v1) {
                        v2 = v1; i2 = i1;
                        if (v > v0) { v1 = v0; i1 = i0; v0 = v; i0 = e; }
                        else        { v1 = v;  i1 = e; }
                    } else { v2 = v; i2 = e; }
                } else { v3 = v; i3 = e; }
            }
        }
        cval[t * 33 + g * 4 + 0] = v0; cidx[t * 33 + g * 4 + 0] = i0;
        cval[t * 33 + g * 4 + 1] = v1; cidx[t * 33 + g * 4 + 1] = i1;
        cval[t * 33 + g * 4 + 2] = v2; cidx[t * 33 + g * 4 + 2] = i2;
        cval[t * 33 + g * 4 + 3] = v3; cidx[t * 33 + g * 4 + 3] = i3;
    }
    __syncthreads();

    if (tid < TOKB) {
        const int t = tid;
        float m0 = -1e30f, m1 = -1e30f, m2 = -1e30f, m3 = -1e30f;
        int   j0 = 0, j1 = 0, j2 = 0, j3 = 0;
#pragma unroll
        for (int q = 0; q < 32; ++q) {   // group-major, ascending e within group
            const float v = cval[t * 33 + q];
            const int   e = cidx[t * 33 + q];
            if (v > m3) {
                if (v > m2) {
                    m3 = m2; j3 = j2;
                    if (v > m1) {
                        m2 = m1; j2 = j1;
                        if (v > m0) { m1 = m0; j1 = j0; m0 = v; j0 = e; }
                        else        { m1 = v;  j1 = e; }
                    } else { m2 = v; j2 = e; }
                } else { m3 = v; j3 = e; }
            }
        }
        const float x1 = expf(m1 - m0), x2 = expf(m2 - m0), x3 = expf(m3 - m0);
        const float inv = 1.f / (1.f + x1 + x2 + x3);
        sval[t][0] = inv;      sidx[t][0] = j0;
        sval[t][1] = x1 * inv; sidx[t][1] = j1;
        sval[t][2] = x2 * inv; sidx[t][2] = j2;
        sval[t][3] = x3 * inv; sidx[t][3] = j3;
        atomicAdd(&hist[j0], 1); atomicAdd(&hist[j1], 1);
        atomicAdd(&hist[j2], 1); atomicAdd(&hist[j3], 1);
    }
    __syncthreads();

    // dense score scatter: overwrite P0 region with final scores
#pragma unroll
    for (int it = 0; it < 16; ++it) {
        const int flat = it * 512 + tid;
        const int t = flat >> 7, e = flat & 127;
        float val = 0.f;
        val = (e == sidx[t][0]) ? sval[t][0] : val;
        val = (e == sidx[t][1]) ? sval[t][1] : val;
        val = (e == sidx[t][2]) ? sval[t][2] : val;
        val = (e == sidx[t][3]) ? sval[t][3] : val;
        scores[base + flat] = val;
    }
    if (tid < TOKB * 4)
        idxOut[(size_t)tb * TOKB * 4 + tid] = (float)sidx[tid >> 2][tid & 3];
    if (tid < NE) {
        const int c = hist[tid];
        if (c) atomicAdd(&counts[tid], (float)c);
    }
}

extern "C" void kernel_launch(void* const* d_in, const int* in_sizes, int n_in,
                              void* d_out, int out_size, void* d_ws, size_t ws_size,
                              hipStream_t stream) {
    const float* A = (const float*)d_in[0];   // hidden_states [T, 2880]
    const float* W = (const float*)d_in[1];   // weight [128, 2880]
    const float* B = (const float*)d_in[2];   // bias [128]
    const int T = in_sizes[0] / HID;          // 16384

    float* out = (float*)d_out;
    float* scores = out;                          // [T,128] (also holds P0)
    float* idxOut = out + (size_t)T * NE;         // [T,4] as float
    float* counts = idxOut + (size_t)T * 4;       // [128] as float

    _Float16* whi = (_Float16*)d_ws;              // [45][2][128][32] halves
    _Float16* wlo = whi + (size_t)NE * HID;
    float* p1 = (float*)(wlo + (size_t)NE * HID); // [T,128] partial ks=1
    float* p2 = p1 + (size_t)T * NE;              // [T,128] partial ks=2

    hipMemsetAsync(counts, 0, NE * sizeof(float), stream);

    hipLaunchKernelGGL(prep_w, dim3(NE), dim3(256), 0, stream, W, whi, wlo);
    hipLaunchKernelGGL(fused_router, dim3((T / TOKB) * 3), dim3(256), 0, stream,
                       A, whi, wlo, scores, p1, p2);
    hipLaunchKernelGGL(reduce_router, dim3(T / TOKB), dim3(512), 0, stream,
                       scores, p1, p2, B, idxOut, counts);
}